// Round 1
// baseline (428.960 us; speedup 1.0000x reference)
//
#include <hip/hip_runtime.h>

#define NR 4096

typedef __attribute__((ext_vector_type(8))) short bf16x8;
typedef __attribute__((ext_vector_type(4))) float f32x4;

__device__ __forceinline__ unsigned short f2bf(float f) {
    union { float f; unsigned u; } v; v.f = f;
    unsigned r = v.u + 0x7fffu + ((v.u >> 16) & 1u);
    return (unsigned short)(r >> 16);
}

// ---------------------------------------------------------------------------
// C[M,64] = A[M,K] @ B[K,64].  A is f32 (optionally a fused pair
// w0*A1 + w1*A2 + b, element-wise, folded during staging).  B is f32 or bf16.
// Split-K: block (mt, sp) computes K-tiles [sp*tps, min(..., ktiles)) and
// writes a full partial C tile to Cpart[sp].  Deterministic (no atomics).
// Tile: BM=64, BN=64, BK=64; 4 waves in 2x2; mfma_f32_16x16x32_bf16.
// LDS layout: row-major 64 bf16/row, 16B chunks XOR-swizzled: chunk kb of
// row r lives at r*64 + ((kb ^ (r&7))<<3)  -> <=2-way bank conflicts.
// ---------------------------------------------------------------------------
template<bool DUAL, bool B_F32>
__global__ __launch_bounds__(256) void gemm_n64(
    const float* __restrict__ A1, const float* __restrict__ A2,
    const void* __restrict__ Bv, float* __restrict__ Cpart,
    const float* __restrict__ wconv, const float* __restrict__ bconv,
    const int K, const int ktiles_total, const int tiles_per_split)
{
    __shared__ unsigned short As[64 * 64];
    __shared__ unsigned short Bs[64 * 64];
    const int t = threadIdx.x;
    const int mt = blockIdx.x, sp = blockIdx.y;
    const int kt0 = sp * tiles_per_split;
    int kt1 = kt0 + tiles_per_split; if (kt1 > ktiles_total) kt1 = ktiles_total;

    float w0 = 0.f, w1 = 0.f, bb = 0.f;
    if (DUAL) { w0 = wconv[0]; w1 = wconv[1]; bb = bconv[0]; }

    // staging maps
    const int ar = t >> 2, ac = (t & 3) << 4;   // A: row, 16-col chunk
    const int bn = t & 63, bk4 = t >> 6;        // B: col, 16-k chunk
    // compute maps
    const int l = t & 63, w = t >> 6;
    const int wm = (w >> 1) << 5, wn = (w & 1) << 5;
    const int lr = l & 15, lk = l >> 4;

    const float* Arow1 = A1 + (size_t)(mt * 64 + ar) * K;
    const float* Arow2 = DUAL ? (A2 + (size_t)(mt * 64 + ar) * K) : A1;

    f32x4 acc[2][2];
    #pragma unroll
    for (int i = 0; i < 2; ++i)
        #pragma unroll
        for (int j = 0; j < 2; ++j)
            #pragma unroll
            for (int r = 0; r < 4; ++r) acc[i][j][r] = 0.f;

    unsigned short regA[16] __attribute__((aligned(16)));
    unsigned short regB[16] __attribute__((aligned(16)));
    unsigned short nxtA[16] __attribute__((aligned(16)));
    unsigned short nxtB[16] __attribute__((aligned(16)));

    auto load_tile = [&](int kt, unsigned short* av, unsigned short* bv) {
        const int k0 = kt << 6;
        #pragma unroll
        for (int j = 0; j < 16; j += 4) {
            const int k = k0 + ac + j;
            f32x4 x1, x2;
            if (k + 3 < K) {
                x1 = *(const f32x4*)(Arow1 + k);
                if (DUAL) x2 = *(const f32x4*)(Arow2 + k);
            } else {
                #pragma unroll
                for (int e = 0; e < 4; ++e) {
                    x1[e] = (k + e < K) ? Arow1[k + e] : 0.f;
                    x2[e] = (DUAL && (k + e < K)) ? Arow2[k + e] : 0.f;
                }
            }
            #pragma unroll
            for (int e = 0; e < 4; ++e) {
                const float vv = DUAL ? (w0 * x1[e] + w1 * x2[e] + bb) : x1[e];
                av[j + e] = f2bf(vv);
            }
        }
        #pragma unroll
        for (int j = 0; j < 16; ++j) {
            const int k = k0 + (bk4 << 4) + j;
            if (B_F32) {
                const float vb = (k < K) ? ((const float*)Bv)[(size_t)k * 64 + bn] : 0.f;
                bv[j] = f2bf(vb);
            } else {
                bv[j] = (k < K) ? ((const unsigned short*)Bv)[(size_t)k * 64 + bn]
                                : (unsigned short)0;
            }
        }
    };

    if (kt0 < kt1) load_tile(kt0, regA, regB);

    for (int kt = kt0; kt < kt1; ++kt) {
        {   // regs -> LDS (swizzled)
            const int kb0 = ac >> 3;
            *(bf16x8*)&As[ar * 64 + (((kb0    ) ^ (ar & 7)) << 3)] = *(bf16x8*)&regA[0];
            *(bf16x8*)&As[ar * 64 + (((kb0 + 1) ^ (ar & 7)) << 3)] = *(bf16x8*)&regA[8];
            const int kbB = bk4 << 1;
            *(bf16x8*)&Bs[bn * 64 + (((kbB    ) ^ (bn & 7)) << 3)] = *(bf16x8*)&regB[0];
            *(bf16x8*)&Bs[bn * 64 + (((kbB + 1) ^ (bn & 7)) << 3)] = *(bf16x8*)&regB[8];
        }
        __syncthreads();
        const bool more = (kt + 1 < kt1);
        if (more) load_tile(kt + 1, nxtA, nxtB);   // T14: issue next loads under MFMA
        #pragma unroll
        for (int ks = 0; ks < 2; ++ks) {
            bf16x8 af[2], bfv[2];
            #pragma unroll
            for (int i = 0; i < 2; ++i) {
                const int row = wm + (i << 4) + lr;
                af[i]  = *(const bf16x8*)&As[row * 64 + ((((ks << 2) + lk) ^ (row & 7)) << 3)];
                const int col = wn + (i << 4) + lr;
                bfv[i] = *(const bf16x8*)&Bs[col * 64 + ((((ks << 2) + lk) ^ (col & 7)) << 3)];
            }
            #pragma unroll
            for (int i = 0; i < 2; ++i)
                #pragma unroll
                for (int j = 0; j < 2; ++j)
                    acc[i][j] = __builtin_amdgcn_mfma_f32_16x16x32_bf16(af[i], bfv[j], acc[i][j], 0, 0, 0);
        }
        __syncthreads();
        if (more) {
            #pragma unroll
            for (int j = 0; j < 16; ++j) { regA[j] = nxtA[j]; regB[j] = nxtB[j]; }
        }
    }

    float* Cp = Cpart + (size_t)sp * (NR * 64);
    #pragma unroll
    for (int i = 0; i < 2; ++i)
        #pragma unroll
        for (int j = 0; j < 2; ++j)
            #pragma unroll
            for (int r = 0; r < 4; ++r) {
                const int row = mt * 64 + wm + (i << 4) + (lk << 2) + r;
                const int col = wn + (j << 4) + lr;
                Cp[(size_t)row * 64 + col] = acc[i][j][r];
            }
}

// sum KS split partials; output f32 or bf16
template<bool OUT_BF16>
__global__ __launch_bounds__(256) void reduce_split(
    const float* __restrict__ Cpart, void* __restrict__ out, const int KS)
{
    const int idx = (blockIdx.x * 256 + threadIdx.x) * 4;
    f32x4 s; s[0] = s[1] = s[2] = s[3] = 0.f;
    for (int sp = 0; sp < KS; ++sp)
        s += *(const f32x4*)(Cpart + (size_t)sp * (NR * 64) + idx);
    if (OUT_BF16) {
        unsigned short* o = (unsigned short*)out;
        #pragma unroll
        for (int e = 0; e < 4; ++e) o[idx + e] = f2bf(s[e]);
    } else {
        *(f32x4*)((float*)out + idx) = s;
    }
}

// rec[M,Nw] = Tb[M,64](bf16) @ Wd[64,Nw](f32).  K=64: single tile, no loop.
__global__ __launch_bounds__(256) void gemm_rec(
    const unsigned short* __restrict__ Tb, const float* __restrict__ Wd,
    float* __restrict__ C, const int Nw)
{
    __shared__ unsigned short As[64 * 64];
    __shared__ unsigned short Bs[64 * 64];
    const int t = threadIdx.x, mt = blockIdx.x, nt = blockIdx.y;
    const int ar = t >> 2, ac = (t & 3) << 4;
    const int bn = t & 63, bk4 = t >> 6;
    const int l = t & 63, w = t >> 6;
    const int wm = (w >> 1) << 5, wn = (w & 1) << 5;
    const int lr = l & 15, lk = l >> 4;

    {
        const bf16x8 v0 = *(const bf16x8*)&Tb[(size_t)(mt * 64 + ar) * 64 + ac];
        const bf16x8 v1 = *(const bf16x8*)&Tb[(size_t)(mt * 64 + ar) * 64 + ac + 8];
        const int kb0 = ac >> 3;
        *(bf16x8*)&As[ar * 64 + (((kb0    ) ^ (ar & 7)) << 3)] = v0;
        *(bf16x8*)&As[ar * 64 + (((kb0 + 1) ^ (ar & 7)) << 3)] = v1;
    }
    {
        unsigned short bv[16] __attribute__((aligned(16)));
        const int col = nt * 64 + bn;
        #pragma unroll
        for (int j = 0; j < 16; ++j) {
            const int k = (bk4 << 4) + j;
            bv[j] = (col < Nw) ? f2bf(Wd[(size_t)k * Nw + col]) : (unsigned short)0;
        }
        const int kbB = bk4 << 1;
        *(bf16x8*)&Bs[bn * 64 + (((kbB    ) ^ (bn & 7)) << 3)] = *(bf16x8*)&bv[0];
        *(bf16x8*)&Bs[bn * 64 + (((kbB + 1) ^ (bn & 7)) << 3)] = *(bf16x8*)&bv[8];
    }
    __syncthreads();

    f32x4 acc[2][2];
    #pragma unroll
    for (int i = 0; i < 2; ++i)
        #pragma unroll
        for (int j = 0; j < 2; ++j)
            #pragma unroll
            for (int r = 0; r < 4; ++r) acc[i][j][r] = 0.f;

    #pragma unroll
    for (int ks = 0; ks < 2; ++ks) {
        bf16x8 af[2], bfv[2];
        #pragma unroll
        for (int i = 0; i < 2; ++i) {
            const int row = wm + (i << 4) + lr;
            af[i]  = *(const bf16x8*)&As[row * 64 + ((((ks << 2) + lk) ^ (row & 7)) << 3)];
            const int col = wn + (i << 4) + lr;
            bfv[i] = *(const bf16x8*)&Bs[col * 64 + ((((ks << 2) + lk) ^ (col & 7)) << 3)];
        }
        #pragma unroll
        for (int i = 0; i < 2; ++i)
            #pragma unroll
            for (int j = 0; j < 2; ++j)
                acc[i][j] = __builtin_amdgcn_mfma_f32_16x16x32_bf16(af[i], bfv[j], acc[i][j], 0, 0, 0);
    }

    #pragma unroll
    for (int i = 0; i < 2; ++i)
        #pragma unroll
        for (int j = 0; j < 2; ++j)
            #pragma unroll
            for (int r = 0; r < 4; ++r) {
                const int row = mt * 64 + wm + (i << 4) + (lk << 2) + r;
                const int col = nt * 64 + wn + (j << 4) + lr;
                if (col < Nw) C[(size_t)row * Nw + col] = acc[i][j][r];
            }
}

// CED: emb = gc + alpha * (relu(LN(gc)@W1 + b1)@W2 + b2), one wave per row
__global__ __launch_bounds__(256) void ced_kernel(
    const float* __restrict__ gc, const float* __restrict__ g, const float* __restrict__ be,
    const float* __restrict__ W1, const float* __restrict__ b1,
    const float* __restrict__ W2, const float* __restrict__ b2,
    const float* __restrict__ alpha, float* __restrict__ emb)
{
    __shared__ float ln_s[4][64];
    __shared__ float h_s[4][32];
    const int w = threadIdx.x >> 6, l = threadIdx.x & 63;
    const int row = blockIdx.x * 4 + w;
    const float x = gc[(size_t)row * 64 + l];
    float s = x, s2 = x * x;
    #pragma unroll
    for (int off = 32; off >= 1; off >>= 1) {
        s  += __shfl_xor(s, off);
        s2 += __shfl_xor(s2, off);
    }
    const float mu  = s * (1.f / 64.f);
    const float var = s2 * (1.f / 64.f) - mu * mu;
    const float ln = (x - mu) * rsqrtf(var + 1e-5f) * g[l] + be[l];
    ln_s[w][l] = ln;
    __syncthreads();
    if (l < 32) {
        float h = b1[l];
        #pragma unroll 8
        for (int k = 0; k < 64; ++k) h += ln_s[w][k] * W1[k * 32 + l];
        h_s[w][l] = fmaxf(h, 0.f);
    }
    __syncthreads();
    float e = b2[l];
    #pragma unroll 8
    for (int j = 0; j < 32; ++j) e += h_s[w][j] * W2[j * 64 + l];
    emb[(size_t)row * 64 + l] = x + alpha[0] * e;
}

// fusion MLP: comb = (cat @ Wfc1 + b1) @ Wfc2 + b2; emits f32 + bf16 copies
__global__ __launch_bounds__(256) void fusion_kernel(
    const float* __restrict__ emb_base, const float* __restrict__ Wfc1,
    const float* __restrict__ bfc1, const float* __restrict__ Wfc2,
    const float* __restrict__ bfc2, float* __restrict__ comb,
    unsigned short* __restrict__ combb)
{
    __shared__ float cat_s[4][192];
    __shared__ float h_s[4][64];
    const int w = threadIdx.x >> 6, l = threadIdx.x & 63;
    const int row = blockIdx.x * 4 + w;
    cat_s[w][l]       = emb_base[(size_t)row * 64 + l];
    cat_s[w][64 + l]  = emb_base[(size_t)(NR * 64) + (size_t)row * 64 + l];
    cat_s[w][128 + l] = emb_base[(size_t)(2 * NR * 64) + (size_t)row * 64 + l];
    __syncthreads();
    float h = bfc1[l];
    #pragma unroll 8
    for (int k = 0; k < 192; ++k) h += cat_s[w][k] * Wfc1[k * 64 + l];
    h_s[w][l] = h;
    __syncthreads();
    float c = bfc2[l];
    #pragma unroll 8
    for (int j = 0; j < 64; ++j) c += h_s[w][j] * Wfc2[j * 64 + l];
    comb[(size_t)row * 64 + l] = c;
    combb[(size_t)row * 64 + l] = f2bf(c);
}

extern "C" void kernel_launch(void* const* d_in, const int* in_sizes, int n_in,
                              void* d_out, int out_size, void* d_ws, size_t ws_size,
                              hipStream_t stream)
{
    const int Din[3] = {3000, 1000, 500};
    const float* feat[3]   = {(const float*)d_in[0], (const float*)d_in[1], (const float*)d_in[2]};
    const float* adj_sp[3] = {(const float*)d_in[3], (const float*)d_in[5], (const float*)d_in[7]};
    const float* adj_ft[3] = {(const float*)d_in[4], (const float*)d_in[6], (const float*)d_in[8]};
    const int base[3] = {9, 20, 31};
    const float *wconv[3], *bconv[3], *Wenc[3], *g[3], *be[3], *W1[3], *b1[3],
                *W2[3], *b2[3], *alpha[3], *Wdec[3];
    for (int i = 0; i < 3; ++i) {
        wconv[i] = (const float*)d_in[base[i] + 0];
        bconv[i] = (const float*)d_in[base[i] + 1];
        Wenc[i]  = (const float*)d_in[base[i] + 2];
        g[i]     = (const float*)d_in[base[i] + 3];
        be[i]    = (const float*)d_in[base[i] + 4];
        W1[i]    = (const float*)d_in[base[i] + 5];
        b1[i]    = (const float*)d_in[base[i] + 6];
        W2[i]    = (const float*)d_in[base[i] + 7];
        b2[i]    = (const float*)d_in[base[i] + 8];
        alpha[i] = (const float*)d_in[base[i] + 9];
        Wdec[i]  = (const float*)d_in[base[i] + 10];
    }
    const float* Wfc1 = (const float*)d_in[42];
    const float* bfc1 = (const float*)d_in[43];
    const float* Wfc2 = (const float*)d_in[44];
    const float* bfc2 = (const float*)d_in[45];

    // workspace layout
    char* wsb = (char*)d_ws;
    const size_t SZ_BF = (size_t)NR * 64 * 2;   // 512 KB
    const size_t SZ_F  = (size_t)NR * 64 * 4;   // 1 MB
    unsigned short* feb[3]; float* gcf[3]; unsigned short* Tb[3];
    for (int i = 0; i < 3; ++i) feb[i] = (unsigned short*)(wsb + (size_t)i * SZ_BF);
    unsigned short* combb = (unsigned short*)(wsb + 3 * SZ_BF);
    for (int i = 0; i < 3; ++i) gcf[i] = (float*)(wsb + 4 * SZ_BF + (size_t)i * SZ_F);
    for (int i = 0; i < 3; ++i) Tb[i] = (unsigned short*)(wsb + 4 * SZ_BF + 3 * SZ_F + (size_t)i * SZ_BF);
    float* Cpart = (float*)(wsb + 7 * SZ_BF + 3 * SZ_F);

    int KScap = (int)((ws_size - (7 * SZ_BF + 3 * SZ_F)) / SZ_F);
    if (KScap > 16) KScap = 16;
    if (KScap < 1) KScap = 1;

    float* out = (float*)d_out;
    float* emb_out  = out;
    float* comb_out = out + 3 * (size_t)NR * 64;
    float* rec_out[3];
    rec_out[0] = out + 4 * (size_t)NR * 64;
    rec_out[1] = rec_out[0] + (size_t)NR * Din[0];
    rec_out[2] = rec_out[1] + (size_t)NR * Din[1];

    // 1) fe_i = feat_i @ W_enc_i  (bf16)
    for (int i = 0; i < 3; ++i) {
        const int kt = (Din[i] + 63) >> 6;
        const int tps = (kt + KScap - 1) / KScap;
        const int KS = (kt + tps - 1) / tps;
        gemm_n64<false, true><<<dim3(64, KS), 256, 0, stream>>>(
            feat[i], nullptr, Wenc[i], Cpart, nullptr, nullptr, Din[i], kt, tps);
        reduce_split<true><<<256, 256, 0, stream>>>(Cpart, feb[i], KS);
    }
    // 2) gc_i = (w0*adj_sp + w1*adj_ft + b) @ fe_i ; CED -> emb_i
    for (int i = 0; i < 3; ++i) {
        const int kt = 64;
        const int tps = (kt + KScap - 1) / KScap;
        const int KS = (kt + tps - 1) / tps;
        gemm_n64<true, false><<<dim3(64, KS), 256, 0, stream>>>(
            adj_sp[i], adj_ft[i], feb[i], Cpart, wconv[i], bconv[i], NR, kt, tps);
        reduce_split<false><<<256, 256, 0, stream>>>(Cpart, gcf[i], KS);
        ced_kernel<<<NR / 4, 256, 0, stream>>>(gcf[i], g[i], be[i], W1[i], b1[i],
                                               W2[i], b2[i], alpha[i],
                                               emb_out + (size_t)i * NR * 64);
    }
    // 3) fusion MLP -> comb
    fusion_kernel<<<NR / 4, 256, 0, stream>>>(emb_out, Wfc1, bfc1, Wfc2, bfc2,
                                              comb_out, combb);
    // 4) T_i = adj_sp_i @ comb  (bf16)   [rec = (adj@comb)@Wdec associativity]
    for (int i = 0; i < 3; ++i) {
        const int kt = 64;
        const int tps = (kt + KScap - 1) / KScap;
        const int KS = (kt + tps - 1) / tps;
        gemm_n64<false, false><<<dim3(64, KS), 256, 0, stream>>>(
            adj_sp[i], nullptr, combb, Cpart, nullptr, nullptr, NR, kt, tps);
        reduce_split<true><<<256, 256, 0, stream>>>(Cpart, Tb[i], KS);
    }
    // 5) rec_i = T_i @ W_dec_i
    for (int i = 0; i < 3; ++i) {
        const int NT = (Din[i] + 63) >> 6;
        gemm_rec<<<dim3(64, NT), 256, 0, stream>>>(Tb[i], Wdec[i], rec_out[i], Din[i]);
    }
}

// Round 2
// 380.406 us; speedup vs baseline: 1.1276x; 1.1276x over previous
//
#include <hip/hip_runtime.h>

#define NR 4096

typedef __attribute__((ext_vector_type(8))) short bf16x8;
typedef __attribute__((ext_vector_type(4))) float f32x4;

struct P3 { const float* p[3]; };
struct V3 { const void* p[3]; };
struct O3 { float* p[3]; };
struct I3 { int v[3]; };

__device__ __forceinline__ unsigned short f2bf(float f) {
    union { float f; unsigned u; } v; v.f = f;
    unsigned r = v.u + 0x7fffu + ((v.u >> 16) & 1u);
    return (unsigned short)(r >> 16);
}

// ---------------------------------------------------------------------------
// C[M,64] = A[M,K] @ B[K,64], z-merged over 3 omics.  A is f32 (optionally a
// fused pair w0*A1 + w1*A2 + b folded during staging).  B is f32 or bf16.
// Split-K: block (mt, sp, z) computes K-tiles [sp*tps_z, ...) and writes a
// partial C tile to Cpart[z*KScap + sp].  Deterministic (no atomics).
// Tile: BM=64, BN=64, BK=64; 4 waves 2x2; mfma_f32_16x16x32_bf16.
// LDS: row-major 64 bf16/row, 16B chunks XOR-swizzled (<=2-way conflicts).
// ---------------------------------------------------------------------------
template<bool DUAL, bool B_F32>
__global__ __launch_bounds__(256) void gemm_n64(
    P3 A1a, P3 A2a, V3 Ba, float* __restrict__ Cpart,
    P3 wca, P3 bca, I3 Kz, I3 ktz, I3 tpsz, const int KScap)
{
    const int z = blockIdx.z;
    const int K = Kz.v[z], ktiles = ktz.v[z], tps = tpsz.v[z];
    const int mt = blockIdx.x, sp = blockIdx.y;
    const int kt0 = sp * tps;
    int kt1 = kt0 + tps; if (kt1 > ktiles) kt1 = ktiles;
    if (kt0 >= kt1) return;                    // uniform early-exit (no syncs yet)

    __shared__ unsigned short As[64 * 64];
    __shared__ unsigned short Bs[64 * 64];
    const int t = threadIdx.x;

    const float* __restrict__ A1 = A1a.p[z];
    const float* __restrict__ A2 = DUAL ? A2a.p[z] : A1a.p[z];
    const void*  __restrict__ Bv = Ba.p[z];

    float w0 = 0.f, w1 = 0.f, bb = 0.f;
    if (DUAL) { w0 = wca.p[z][0]; w1 = wca.p[z][1]; bb = bca.p[z][0]; }

    // staging maps
    const int ar = t >> 2, ac = (t & 3) << 4;   // A: row, 16-col chunk
    const int bn = t & 63, bk4 = t >> 6;        // B: col, 16-k chunk
    // compute maps
    const int l = t & 63, w = t >> 6;
    const int wm = (w >> 1) << 5, wn = (w & 1) << 5;
    const int lr = l & 15, lk = l >> 4;

    const float* Arow1 = A1 + (size_t)(mt * 64 + ar) * K;
    const float* Arow2 = A2 + (size_t)(mt * 64 + ar) * K;

    f32x4 acc[2][2];
    #pragma unroll
    for (int i = 0; i < 2; ++i)
        #pragma unroll
        for (int j = 0; j < 2; ++j)
            #pragma unroll
            for (int r = 0; r < 4; ++r) acc[i][j][r] = 0.f;

    unsigned short regA[16] __attribute__((aligned(16)));
    unsigned short regB[16] __attribute__((aligned(16)));
    unsigned short nxtA[16] __attribute__((aligned(16)));
    unsigned short nxtB[16] __attribute__((aligned(16)));

    auto load_tile = [&](int kt, unsigned short* av, unsigned short* bv) {
        const int k0 = kt << 6;
        #pragma unroll
        for (int j = 0; j < 16; j += 4) {
            const int k = k0 + ac + j;
            f32x4 x1, x2;
            if (k + 3 < K) {
                x1 = *(const f32x4*)(Arow1 + k);
                if (DUAL) x2 = *(const f32x4*)(Arow2 + k);
            } else {
                #pragma unroll
                for (int e = 0; e < 4; ++e) {
                    x1[e] = (k + e < K) ? Arow1[k + e] : 0.f;
                    x2[e] = (DUAL && (k + e < K)) ? Arow2[k + e] : 0.f;
                }
            }
            #pragma unroll
            for (int e = 0; e < 4; ++e) {
                const float vv = DUAL ? (w0 * x1[e] + w1 * x2[e] + bb) : x1[e];
                av[j + e] = f2bf(vv);
            }
        }
        #pragma unroll
        for (int j = 0; j < 16; ++j) {
            const int k = k0 + (bk4 << 4) + j;
            if (B_F32) {
                const float vb = (k < K) ? ((const float*)Bv)[(size_t)k * 64 + bn] : 0.f;
                bv[j] = f2bf(vb);
            } else {
                bv[j] = (k < K) ? ((const unsigned short*)Bv)[(size_t)k * 64 + bn]
                                : (unsigned short)0;
            }
        }
    };

    load_tile(kt0, regA, regB);

    for (int kt = kt0; kt < kt1; ++kt) {
        {   // regs -> LDS (swizzled)
            const int kb0 = ac >> 3;
            *(bf16x8*)&As[ar * 64 + (((kb0    ) ^ (ar & 7)) << 3)] = *(bf16x8*)&regA[0];
            *(bf16x8*)&As[ar * 64 + (((kb0 + 1) ^ (ar & 7)) << 3)] = *(bf16x8*)&regA[8];
            const int kbB = bk4 << 1;
            *(bf16x8*)&Bs[bn * 64 + (((kbB    ) ^ (bn & 7)) << 3)] = *(bf16x8*)&regB[0];
            *(bf16x8*)&Bs[bn * 64 + (((kbB + 1) ^ (bn & 7)) << 3)] = *(bf16x8*)&regB[8];
        }
        __syncthreads();
        const bool more = (kt + 1 < kt1);
        if (more) load_tile(kt + 1, nxtA, nxtB);   // issue next loads under MFMA
        #pragma unroll
        for (int ks = 0; ks < 2; ++ks) {
            bf16x8 af[2], bfv[2];
            #pragma unroll
            for (int i = 0; i < 2; ++i) {
                const int row = wm + (i << 4) + lr;
                af[i]  = *(const bf16x8*)&As[row * 64 + ((((ks << 2) + lk) ^ (row & 7)) << 3)];
                const int col = wn + (i << 4) + lr;
                bfv[i] = *(const bf16x8*)&Bs[col * 64 + ((((ks << 2) + lk) ^ (col & 7)) << 3)];
            }
            #pragma unroll
            for (int i = 0; i < 2; ++i)
                #pragma unroll
                for (int j = 0; j < 2; ++j)
                    acc[i][j] = __builtin_amdgcn_mfma_f32_16x16x32_bf16(af[i], bfv[j], acc[i][j], 0, 0, 0);
        }
        __syncthreads();
        if (more) {
            #pragma unroll
            for (int j = 0; j < 16; ++j) { regA[j] = nxtA[j]; regB[j] = nxtB[j]; }
        }
    }

    float* Cp = Cpart + (size_t)(z * KScap + sp) * (NR * 64);
    #pragma unroll
    for (int i = 0; i < 2; ++i)
        #pragma unroll
        for (int j = 0; j < 2; ++j)
            #pragma unroll
            for (int r = 0; r < 4; ++r) {
                const int row = mt * 64 + wm + (i << 4) + (lk << 2) + r;
                const int col = wn + (j << 4) + lr;
                Cp[(size_t)row * 64 + col] = acc[i][j][r];
            }
}

// sum per-z split partials -> bf16, z-merged (grid.y = z)
__global__ __launch_bounds__(256) void reduce_many(
    const float* __restrict__ Cpart, unsigned short* __restrict__ out,
    I3 nsp, const int KScap)
{
    const int z = blockIdx.y;
    const int idx = (blockIdx.x * 256 + threadIdx.x) * 4;
    const float* base = Cpart + (size_t)z * KScap * (NR * 64);
    const int n = nsp.v[z];
    f32x4 s; s[0] = s[1] = s[2] = s[3] = 0.f;
    for (int sp = 0; sp < n; ++sp)
        s += *(const f32x4*)(base + (size_t)sp * (NR * 64) + idx);
    unsigned short* o = out + (size_t)z * (NR * 64);
    #pragma unroll
    for (int e = 0; e < 4; ++e) o[idx + e] = f2bf(s[e]);
}

// split-reduce fused with CED: gc = sum(partials);
// emb = gc + alpha * (relu(LN(gc)@W1 + b1)@W2 + b2).  One wave per row.
__global__ __launch_bounds__(256) void reduce_ced(
    const float* __restrict__ Cpart, P3 ga, P3 bea, P3 W1a, P3 b1a,
    P3 W2a, P3 b2a, P3 ala, float* __restrict__ emb_out,
    I3 nsp, const int KScap)
{
    __shared__ float ln_s[4][64];
    __shared__ float h_s[4][32];
    const int z = blockIdx.y;
    const int w = threadIdx.x >> 6, l = threadIdx.x & 63;
    const int row = blockIdx.x * 4 + w;
    const float* base = Cpart + (size_t)z * KScap * (NR * 64);
    const int n = nsp.v[z];
    float x = 0.f;
    for (int sp = 0; sp < n; ++sp)
        x += base[(size_t)sp * (NR * 64) + (size_t)row * 64 + l];

    float s = x, s2 = x * x;
    #pragma unroll
    for (int off = 32; off >= 1; off >>= 1) {
        s  += __shfl_xor(s, off);
        s2 += __shfl_xor(s2, off);
    }
    const float mu  = s * (1.f / 64.f);
    const float var = s2 * (1.f / 64.f) - mu * mu;
    const float ln = (x - mu) * rsqrtf(var + 1e-5f) * ga.p[z][l] + bea.p[z][l];
    ln_s[w][l] = ln;
    __syncthreads();
    if (l < 32) {
        const float* W1 = W1a.p[z];
        float h = b1a.p[z][l];
        #pragma unroll 8
        for (int k = 0; k < 64; ++k) h += ln_s[w][k] * W1[k * 32 + l];
        h_s[w][l] = fmaxf(h, 0.f);
    }
    __syncthreads();
    const float* W2 = W2a.p[z];
    float e = b2a.p[z][l];
    #pragma unroll 8
    for (int j = 0; j < 32; ++j) e += h_s[w][j] * W2[j * 64 + l];
    emb_out[(size_t)z * (NR * 64) + (size_t)row * 64 + l] = x + ala.p[z][0] * e;
}

// fusion MLP: comb = (cat @ Wfc1 + b1) @ Wfc2 + b2; emits f32 + bf16 copies
__global__ __launch_bounds__(256) void fusion_kernel(
    const float* __restrict__ emb_base, const float* __restrict__ Wfc1,
    const float* __restrict__ bfc1, const float* __restrict__ Wfc2,
    const float* __restrict__ bfc2, float* __restrict__ comb,
    unsigned short* __restrict__ combb)
{
    __shared__ float cat_s[4][192];
    __shared__ float h_s[4][64];
    const int w = threadIdx.x >> 6, l = threadIdx.x & 63;
    const int row = blockIdx.x * 4 + w;
    cat_s[w][l]       = emb_base[(size_t)row * 64 + l];
    cat_s[w][64 + l]  = emb_base[(size_t)(NR * 64) + (size_t)row * 64 + l];
    cat_s[w][128 + l] = emb_base[(size_t)(2 * NR * 64) + (size_t)row * 64 + l];
    __syncthreads();
    float h = bfc1[l];
    #pragma unroll 8
    for (int k = 0; k < 192; ++k) h += cat_s[w][k] * Wfc1[k * 64 + l];
    h_s[w][l] = h;
    __syncthreads();
    float c = bfc2[l];
    #pragma unroll 8
    for (int j = 0; j < 64; ++j) c += h_s[w][j] * Wfc2[j * 64 + l];
    comb[(size_t)row * 64 + l] = c;
    combb[(size_t)row * 64 + l] = f2bf(c);
}

// rec[M,Dz] = Tb_z[M,64](bf16) @ Wd_z[64,Dz](f32), z-merged. K=64 single tile.
__global__ __launch_bounds__(256) void gemm_rec(
    const unsigned short* __restrict__ Tbase, P3 Wda, O3 outa, I3 Dz)
{
    const int z = blockIdx.z;
    const int Nw = Dz.v[z];
    const int mt = blockIdx.x, nt = blockIdx.y;
    if (nt * 64 >= Nw) return;                  // uniform early-exit
    __shared__ unsigned short As[64 * 64];
    __shared__ unsigned short Bs[64 * 64];
    const int t = threadIdx.x;
    const unsigned short* Tb = Tbase + (size_t)z * (NR * 64);
    const float* Wd = Wda.p[z];
    float* C = outa.p[z];

    const int ar = t >> 2, ac = (t & 3) << 4;
    const int bn = t & 63, bk4 = t >> 6;
    const int l = t & 63, w = t >> 6;
    const int wm = (w >> 1) << 5, wn = (w & 1) << 5;
    const int lr = l & 15, lk = l >> 4;

    {
        const bf16x8 v0 = *(const bf16x8*)&Tb[(size_t)(mt * 64 + ar) * 64 + ac];
        const bf16x8 v1 = *(const bf16x8*)&Tb[(size_t)(mt * 64 + ar) * 64 + ac + 8];
        const int kb0 = ac >> 3;
        *(bf16x8*)&As[ar * 64 + (((kb0    ) ^ (ar & 7)) << 3)] = v0;
        *(bf16x8*)&As[ar * 64 + (((kb0 + 1) ^ (ar & 7)) << 3)] = v1;
    }
    {
        unsigned short bv[16] __attribute__((aligned(16)));
        const int col = nt * 64 + bn;
        #pragma unroll
        for (int j = 0; j < 16; ++j) {
            const int k = (bk4 << 4) + j;
            bv[j] = (col < Nw) ? f2bf(Wd[(size_t)k * Nw + col]) : (unsigned short)0;
        }
        const int kbB = bk4 << 1;
        *(bf16x8*)&Bs[bn * 64 + (((kbB    ) ^ (bn & 7)) << 3)] = *(bf16x8*)&bv[0];
        *(bf16x8*)&Bs[bn * 64 + (((kbB + 1) ^ (bn & 7)) << 3)] = *(bf16x8*)&bv[8];
    }
    __syncthreads();

    f32x4 acc[2][2];
    #pragma unroll
    for (int i = 0; i < 2; ++i)
        #pragma unroll
        for (int j = 0; j < 2; ++j)
            #pragma unroll
            for (int r = 0; r < 4; ++r) acc[i][j][r] = 0.f;

    #pragma unroll
    for (int ks = 0; ks < 2; ++ks) {
        bf16x8 af[2], bfv[2];
        #pragma unroll
        for (int i = 0; i < 2; ++i) {
            const int row = wm + (i << 4) + lr;
            af[i]  = *(const bf16x8*)&As[row * 64 + ((((ks << 2) + lk) ^ (row & 7)) << 3)];
            const int col = wn + (i << 4) + lr;
            bfv[i] = *(const bf16x8*)&Bs[col * 64 + ((((ks << 2) + lk) ^ (col & 7)) << 3)];
        }
        #pragma unroll
        for (int i = 0; i < 2; ++i)
            #pragma unroll
            for (int j = 0; j < 2; ++j)
                acc[i][j] = __builtin_amdgcn_mfma_f32_16x16x32_bf16(af[i], bfv[j], acc[i][j], 0, 0, 0);
    }

    #pragma unroll
    for (int i = 0; i < 2; ++i)
        #pragma unroll
        for (int j = 0; j < 2; ++j)
            #pragma unroll
            for (int r = 0; r < 4; ++r) {
                const int row = mt * 64 + wm + (i << 4) + (lk << 2) + r;
                const int col = nt * 64 + wn + (j << 4) + lr;
                if (col < Nw) C[(size_t)row * Nw + col] = acc[i][j][r];
            }
}

extern "C" void kernel_launch(void* const* d_in, const int* in_sizes, int n_in,
                              void* d_out, int out_size, void* d_ws, size_t ws_size,
                              hipStream_t stream)
{
    const int Din[3] = {3000, 1000, 500};
    const float* feat[3]   = {(const float*)d_in[0], (const float*)d_in[1], (const float*)d_in[2]};
    const float* adj_sp[3] = {(const float*)d_in[3], (const float*)d_in[5], (const float*)d_in[7]};
    const float* adj_ft[3] = {(const float*)d_in[4], (const float*)d_in[6], (const float*)d_in[8]};
    const int base[3] = {9, 20, 31};
    const float *wconv[3], *bconv[3], *Wenc[3], *g[3], *be[3], *W1[3], *b1[3],
                *W2[3], *b2[3], *alpha[3], *Wdec[3];
    for (int i = 0; i < 3; ++i) {
        wconv[i] = (const float*)d_in[base[i] + 0];
        bconv[i] = (const float*)d_in[base[i] + 1];
        Wenc[i]  = (const float*)d_in[base[i] + 2];
        g[i]     = (const float*)d_in[base[i] + 3];
        be[i]    = (const float*)d_in[base[i] + 4];
        W1[i]    = (const float*)d_in[base[i] + 5];
        b1[i]    = (const float*)d_in[base[i] + 6];
        W2[i]    = (const float*)d_in[base[i] + 7];
        b2[i]    = (const float*)d_in[base[i] + 8];
        alpha[i] = (const float*)d_in[base[i] + 9];
        Wdec[i]  = (const float*)d_in[base[i] + 10];
    }
    const float* Wfc1 = (const float*)d_in[42];
    const float* bfc1 = (const float*)d_in[43];
    const float* Wfc2 = (const float*)d_in[44];
    const float* bfc2 = (const float*)d_in[45];

    // workspace layout: feb[3] | combb | Tb[3]  (bf16, contiguous per group),
    // then Cpart: 3 * KScap * 1 MB
    char* wsb = (char*)d_ws;
    const size_t SZ_BF = (size_t)NR * 64 * 2;   // 512 KB
    const size_t SZ_F  = (size_t)NR * 64 * 4;   // 1 MB
    unsigned short* feb   = (unsigned short*)wsb;                    // 3x
    unsigned short* combb = (unsigned short*)(wsb + 3 * SZ_BF);
    unsigned short* Tb    = (unsigned short*)(wsb + 4 * SZ_BF);      // 3x
    float* Cpart          = (float*)(wsb + 7 * SZ_BF);

    int KScap = (int)((ws_size - 7 * SZ_BF) / (3 * SZ_F));
    if (KScap > 16) KScap = 16;
    if (KScap < 1)  KScap = 1;

    float* out = (float*)d_out;
    float* emb_out  = out;
    float* comb_out = out + 3 * (size_t)NR * 64;
    O3 rec_out;
    rec_out.p[0] = out + 4 * (size_t)NR * 64;
    rec_out.p[1] = rec_out.p[0] + (size_t)NR * Din[0];
    rec_out.p[2] = rec_out.p[1] + (size_t)NR * Din[1];

    auto split_plan = [&](const int* Ks, I3& kt, I3& tps, I3& nsp, int& maxnsp) {
        maxnsp = 0;
        for (int i = 0; i < 3; ++i) {
            const int k = (Ks[i] + 63) >> 6;
            int t = (k + KScap - 1) / KScap;
            if (k >= 2 && k < 32 && t < 2) t = 2;   // avoid Cpart bloat for small K
            kt.v[i] = k; tps.v[i] = t;
            nsp.v[i] = (k + t - 1) / t;
            if (nsp.v[i] > maxnsp) maxnsp = nsp.v[i];
        }
    };

    P3 featA, adjspA, adjftA, wcA, bcA, gA, beA, W1A, b1A, W2A, b2A, alA, WdA, WencA;
    for (int i = 0; i < 3; ++i) {
        featA.p[i] = feat[i]; adjspA.p[i] = adj_sp[i]; adjftA.p[i] = adj_ft[i];
        wcA.p[i] = wconv[i];  bcA.p[i] = bconv[i];
        gA.p[i] = g[i]; beA.p[i] = be[i]; W1A.p[i] = W1[i]; b1A.p[i] = b1[i];
        W2A.p[i] = W2[i]; b2A.p[i] = b2[i]; alA.p[i] = alpha[i];
        WdA.p[i] = Wdec[i]; WencA.p[i] = Wenc[i];
    }
    V3 BencV, BfeV, BcombV;
    for (int i = 0; i < 3; ++i) {
        BencV.p[i]  = Wenc[i];
        BfeV.p[i]   = feb + (size_t)i * NR * 64;
        BcombV.p[i] = combb;
    }
    I3 Kfeat = {Din[0], Din[1], Din[2]};
    I3 Kadj  = {NR, NR, NR};
    I3 Dz    = {Din[0], Din[1], Din[2]};

    I3 ktF, tpsF, nspF; int mF; split_plan(Kfeat.v, ktF, tpsF, nspF, mF);
    I3 ktA, tpsA, nspA; int mA; split_plan(Kadj.v,  ktA, tpsA, nspA, mA);

    // 1) fe_i = feat_i @ W_enc_i  (bf16)
    gemm_n64<false, true><<<dim3(64, mF, 3), 256, 0, stream>>>(
        featA, featA, BencV, Cpart, wcA, bcA, Kfeat, ktF, tpsF, KScap);
    reduce_many<<<dim3(256, 3), 256, 0, stream>>>(Cpart, feb, nspF, KScap);

    // 2) gc_i = (w0*adj_sp + w1*adj_ft + b) @ fe_i ; fused CED -> emb_i
    gemm_n64<true, false><<<dim3(64, mA, 3), 256, 0, stream>>>(
        adjspA, adjftA, BfeV, Cpart, wcA, bcA, Kadj, ktA, tpsA, KScap);
    reduce_ced<<<dim3(NR / 4, 3), 256, 0, stream>>>(
        Cpart, gA, beA, W1A, b1A, W2A, b2A, alA, emb_out, nspA, KScap);

    // 3) fusion MLP -> comb (f32 out + bf16 scratch)
    fusion_kernel<<<NR / 4, 256, 0, stream>>>(emb_out, Wfc1, bfc1, Wfc2, bfc2,
                                              comb_out, combb);

    // 4) T_i = adj_sp_i @ comb  (bf16)   [rec = (adj@comb)@Wdec associativity]
    gemm_n64<false, false><<<dim3(64, mA, 3), 256, 0, stream>>>(
        adjspA, adjspA, BcombV, Cpart, wcA, bcA, Kadj, ktA, tpsA, KScap);
    reduce_many<<<dim3(256, 3), 256, 0, stream>>>(Cpart, Tb, nspA, KScap);

    // 5) rec_i = T_i @ W_dec_i
    const int NTmax = (Din[0] + 63) >> 6;
    gemm_rec<<<dim3(64, NTmax, 3), 256, 0, stream>>>(Tb, WdA, rec_out, Dz);
}

// Round 4
// 250.504 us; speedup vs baseline: 1.7124x; 1.5186x over previous
//
#include <hip/hip_runtime.h>

#define NR 4096

typedef __attribute__((ext_vector_type(8))) short bf16x8;
typedef __attribute__((ext_vector_type(4))) float f32x4;
typedef __attribute__((ext_vector_type(4))) unsigned short u16x4;

struct P3 { const float* p[3]; };
struct V3 { const void* p[3]; };
struct O3 { float* p[3]; };
struct I3 { int v[3]; };

__device__ __forceinline__ unsigned short f2bf(float f) {
    union { float f; unsigned u; } v; v.f = f;
    unsigned r = v.u + 0x7fffu + ((v.u >> 16) & 1u);
    return (unsigned short)(r >> 16);
}

// ---------------------------------------------------------------------------
// C[M,64] = A[M,K] @ B[K,64], z-merged over 3 omics.  A is f32 (optionally a
// fused pair w0*A1 + w1*A2 + b folded during staging).  B is f32 or bf16.
// Split-K partials to Cpart (deterministic).  BM=BN=BK=64, 4 waves 2x2,
// mfma_f32_16x16x32_bf16.
// A staging is INSTRUCTION-contiguous (A is the HBM-heavy stream):
//   step j, thread t -> row j*16+(t>>4), cols (t&15)*4 (f32x4); LDS [m][k].
// B staging is column-mapped (B is small and L2-resident; layout [n][k] is
// what the MFMA fragment read requires — row-loading B would transpose it,
// which was Round 3's correctness bug):
//   thread t -> col t&63, k chunk (t>>6)*16, 16 scalar loads; LDS [n][k].
// LDS: row-major 64 bf16/row; 16B chunk c of row r at ((c ^ (r&7))<<3)
// -> MFMA b128 reads conflict-free.
// ---------------------------------------------------------------------------
template<bool DUAL, bool B_F32>
__global__ __launch_bounds__(256) void gemm_n64(
    P3 A1a, P3 A2a, V3 Ba, float* __restrict__ Cpart,
    P3 wca, P3 bca, I3 Kz, I3 ktz, I3 tpsz, const int KScap)
{
    const int z = blockIdx.z;
    const int K = Kz.v[z], ktiles = ktz.v[z], tps = tpsz.v[z];
    const int mt = blockIdx.x, sp = blockIdx.y;
    const int kt0 = sp * tps;
    int kt1 = kt0 + tps; if (kt1 > ktiles) kt1 = ktiles;
    if (kt0 >= kt1) return;                    // uniform early-exit

    __shared__ unsigned short As[64 * 64];
    __shared__ unsigned short Bs[64 * 64];
    const int t = threadIdx.x;

    const float* __restrict__ A1 = A1a.p[z];
    const float* __restrict__ A2 = DUAL ? A2a.p[z] : A1a.p[z];
    const void*  __restrict__ Bv = Ba.p[z];

    float w0 = 0.f, w1 = 0.f, bb = 0.f;
    if (DUAL) { w0 = wca.p[z][0]; w1 = wca.p[z][1]; bb = bca.p[z][0]; }

    // A staging map: rows j*16+r0, cols c4*4 (instruction-contiguous)
    const int r0 = t >> 4, c4 = t & 15;
    // B staging map: column bn, k-chunk bk4*16 (LDS layout [n][k])
    const int bn = t & 63, bk4 = t >> 6;
    // compute maps
    const int l = t & 63, w = t >> 6;
    const int wm = (w >> 1) << 5, wn = (w & 1) << 5;
    const int lr = l & 15, lk = l >> 4;

    const float* Ab1 = A1 + (size_t)(mt * 64 + r0) * K + c4 * 4;
    const float* Ab2 = A2 + (size_t)(mt * 64 + r0) * K + c4 * 4;

    f32x4 acc[2][2];
    #pragma unroll
    for (int i = 0; i < 2; ++i)
        #pragma unroll
        for (int j = 0; j < 2; ++j)
            #pragma unroll
            for (int r = 0; r < 4; ++r) acc[i][j][r] = 0.f;

    unsigned short regA[16] __attribute__((aligned(16)));   // 4 x u16x4 (row j*16+r0)
    unsigned short regB[16] __attribute__((aligned(16)));   // col bn, k's bk4*16..+15
    unsigned short nxtA[16] __attribute__((aligned(16)));
    unsigned short nxtB[16] __attribute__((aligned(16)));

    auto load_tile = [&](int kt, unsigned short* av, unsigned short* bv) {
        const int k0 = kt << 6;
        // ---- A: 4 (8 if DUAL) f32x4 loads, instruction-contiguous ----
        const int kk = k0 + c4 * 4;
        #pragma unroll
        for (int j = 0; j < 4; ++j) {
            const float* p1 = Ab1 + (size_t)j * 16 * K + k0;
            const float* p2 = Ab2 + (size_t)j * 16 * K + k0;
            f32x4 x1, x2;
            if (kk + 3 < K) {
                x1 = *(const f32x4*)p1;
                if (DUAL) x2 = *(const f32x4*)p2;
            } else {
                #pragma unroll
                for (int e = 0; e < 4; ++e) {
                    x1[e] = (kk + e < K) ? p1[e] : 0.f;
                    x2[e] = (DUAL && (kk + e < K)) ? p2[e] : 0.f;
                }
            }
            #pragma unroll
            for (int e = 0; e < 4; ++e) {
                const float vv = DUAL ? (w0 * x1[e] + w1 * x2[e] + bb) : x1[e];
                av[j * 4 + e] = f2bf(vv);
            }
        }
        // ---- B: per-thread column (L2-resident; layout [n][k]) ----
        #pragma unroll
        for (int j = 0; j < 16; ++j) {
            const int k = k0 + (bk4 << 4) + j;
            if (B_F32) {
                const float vb = (k < K) ? ((const float*)Bv)[(size_t)k * 64 + bn] : 0.f;
                bv[j] = f2bf(vb);
            } else {
                bv[j] = (k < K) ? ((const unsigned short*)Bv)[(size_t)k * 64 + bn]
                                : (unsigned short)0;
            }
        }
    };

    load_tile(kt0, regA, regB);

    // LDS write addresses (constant per thread)
    const int aw_base = r0 * 64 + (((c4 >> 1) ^ (r0 & 7)) << 3) + ((c4 & 1) << 2);
    const int kbB = bk4 << 1;
    const int bw0 = bn * 64 + (((kbB    ) ^ (bn & 7)) << 3);
    const int bw1 = bn * 64 + (((kbB + 1) ^ (bn & 7)) << 3);

    for (int kt = kt0; kt < kt1; ++kt) {
        {   // regs -> LDS (swizzled)
            #pragma unroll
            for (int j = 0; j < 4; ++j)
                *(u16x4*)&As[aw_base + j * 16 * 64] = *(u16x4*)&regA[j * 4];
            *(bf16x8*)&Bs[bw0] = *(bf16x8*)&regB[0];
            *(bf16x8*)&Bs[bw1] = *(bf16x8*)&regB[8];
        }
        __syncthreads();
        const bool more = (kt + 1 < kt1);
        if (more) load_tile(kt + 1, nxtA, nxtB);   // next loads in flight under MFMA
        #pragma unroll
        for (int ks = 0; ks < 2; ++ks) {
            bf16x8 af[2], bfv[2];
            #pragma unroll
            for (int i = 0; i < 2; ++i) {
                const int row = wm + (i << 4) + lr;
                af[i]  = *(const bf16x8*)&As[row * 64 + ((((ks << 2) + lk) ^ (row & 7)) << 3)];
                const int col = wn + (i << 4) + lr;
                bfv[i] = *(const bf16x8*)&Bs[col * 64 + ((((ks << 2) + lk) ^ (col & 7)) << 3)];
            }
            #pragma unroll
            for (int i = 0; i < 2; ++i)
                #pragma unroll
                for (int j = 0; j < 2; ++j)
                    acc[i][j] = __builtin_amdgcn_mfma_f32_16x16x32_bf16(af[i], bfv[j], acc[i][j], 0, 0, 0);
        }
        __syncthreads();
        if (more) {
            #pragma unroll
            for (int j = 0; j < 16; ++j) { regA[j] = nxtA[j]; regB[j] = nxtB[j]; }
        }
    }

    float* Cp = Cpart + (size_t)(z * KScap + sp) * (NR * 64);
    #pragma unroll
    for (int i = 0; i < 2; ++i)
        #pragma unroll
        for (int j = 0; j < 2; ++j)
            #pragma unroll
            for (int r = 0; r < 4; ++r) {
                const int row = mt * 64 + wm + (i << 4) + (lk << 2) + r;
                const int col = wn + (j << 4) + lr;
                Cp[(size_t)row * 64 + col] = acc[i][j][r];
            }
}

// sum per-z split partials -> bf16, z-merged (grid.y = z)
__global__ __launch_bounds__(256) void reduce_many(
    const float* __restrict__ Cpart, unsigned short* __restrict__ out,
    I3 nsp, const int KScap)
{
    const int z = blockIdx.y;
    const int idx = (blockIdx.x * 256 + threadIdx.x) * 4;
    const float* base = Cpart + (size_t)z * KScap * (NR * 64);
    const int n = nsp.v[z];
    f32x4 s; s[0] = s[1] = s[2] = s[3] = 0.f;
    for (int sp = 0; sp < n; ++sp)
        s += *(const f32x4*)(base + (size_t)sp * (NR * 64) + idx);
    unsigned short* o = out + (size_t)z * (NR * 64);
    #pragma unroll
    for (int e = 0; e < 4; ++e) o[idx + e] = f2bf(s[e]);
}

// split-reduce fused with CED: gc = sum(partials);
// emb = gc + alpha * (relu(LN(gc)@W1 + b1)@W2 + b2).  One wave per row.
__global__ __launch_bounds__(256) void reduce_ced(
    const float* __restrict__ Cpart, P3 ga, P3 bea, P3 W1a, P3 b1a,
    P3 W2a, P3 b2a, P3 ala, float* __restrict__ emb_out,
    I3 nsp, const int KScap)
{
    __shared__ float ln_s[4][64];
    __shared__ float h_s[4][32];
    const int z = blockIdx.y;
    const int w = threadIdx.x >> 6, l = threadIdx.x & 63;
    const int row = blockIdx.x * 4 + w;
    const float* base = Cpart + (size_t)z * KScap * (NR * 64);
    const int n = nsp.v[z];
    float x = 0.f;
    for (int sp = 0; sp < n; ++sp)
        x += base[(size_t)sp * (NR * 64) + (size_t)row * 64 + l];

    float s = x, s2 = x * x;
    #pragma unroll
    for (int off = 32; off >= 1; off >>= 1) {
        s  += __shfl_xor(s, off);
        s2 += __shfl_xor(s2, off);
    }
    const float mu  = s * (1.f / 64.f);
    const float var = s2 * (1.f / 64.f) - mu * mu;
    const float ln = (x - mu) * rsqrtf(var + 1e-5f) * ga.p[z][l] + bea.p[z][l];
    ln_s[w][l] = ln;
    __syncthreads();
    if (l < 32) {
        const float* W1 = W1a.p[z];
        float h = b1a.p[z][l];
        #pragma unroll 8
        for (int k = 0; k < 64; ++k) h += ln_s[w][k] * W1[k * 32 + l];
        h_s[w][l] = fmaxf(h, 0.f);
    }
    __syncthreads();
    const float* W2 = W2a.p[z];
    float e = b2a.p[z][l];
    #pragma unroll 8
    for (int j = 0; j < 32; ++j) e += h_s[w][j] * W2[j * 64 + l];
    emb_out[(size_t)z * (NR * 64) + (size_t)row * 64 + l] = x + ala.p[z][0] * e;
}

// fusion MLP: comb = (cat @ Wfc1 + b1) @ Wfc2 + b2; emits f32 + bf16 copies
__global__ __launch_bounds__(256) void fusion_kernel(
    const float* __restrict__ emb_base, const float* __restrict__ Wfc1,
    const float* __restrict__ bfc1, const float* __restrict__ Wfc2,
    const float* __restrict__ bfc2, float* __restrict__ comb,
    unsigned short* __restrict__ combb)
{
    __shared__ float cat_s[4][192];
    __shared__ float h_s[4][64];
    const int w = threadIdx.x >> 6, l = threadIdx.x & 63;
    const int row = blockIdx.x * 4 + w;
    cat_s[w][l]       = emb_base[(size_t)row * 64 + l];
    cat_s[w][64 + l]  = emb_base[(size_t)(NR * 64) + (size_t)row * 64 + l];
    cat_s[w][128 + l] = emb_base[(size_t)(2 * NR * 64) + (size_t)row * 64 + l];
    __syncthreads();
    float h = bfc1[l];
    #pragma unroll 8
    for (int k = 0; k < 192; ++k) h += cat_s[w][k] * Wfc1[k * 64 + l];
    h_s[w][l] = h;
    __syncthreads();
    float c = bfc2[l];
    #pragma unroll 8
    for (int j = 0; j < 64; ++j) c += h_s[w][j] * Wfc2[j * 64 + l];
    comb[(size_t)row * 64 + l] = c;
    combb[(size_t)row * 64 + l] = f2bf(c);
}

// rec[M,Dz] = Tb_z[M,64](bf16) @ Wd_z[64,Dz](f32), z-merged. K=64 single tile.
__global__ __launch_bounds__(256) void gemm_rec(
    const unsigned short* __restrict__ Tbase, P3 Wda, O3 outa, I3 Dz)
{
    const int z = blockIdx.z;
    const int Nw = Dz.v[z];
    const int mt = blockIdx.x, nt = blockIdx.y;
    if (nt * 64 >= Nw) return;                  // uniform early-exit
    __shared__ unsigned short As[64 * 64];
    __shared__ unsigned short Bs[64 * 64];
    const int t = threadIdx.x;
    const unsigned short* Tb = Tbase + (size_t)z * (NR * 64);
    const float* Wd = Wda.p[z];
    float* C = outa.p[z];

    const int r0b = t >> 3, c8 = t & 7;
    const int bn = t & 63, bk4 = t >> 6;
    const int l = t & 63, w = t >> 6;
    const int wm = (w >> 1) << 5, wn = (w & 1) << 5;
    const int lr = l & 15, lk = l >> 4;

    {   // A: instruction-contiguous bf16x8 loads; LDS [m][k]
        #pragma unroll
        for (int j = 0; j < 2; ++j) {
            const int row = j * 32 + r0b;
            const bf16x8 v = *(const bf16x8*)&Tb[(size_t)row * 64 + c8 * 8];
            *(bf16x8*)&As[row * 64 + ((c8 ^ (row & 7)) << 3)] = v;
        }
    }
    {   // B: per-thread column of Wd (L2-resident); LDS [n][k]
        unsigned short bv[16] __attribute__((aligned(16)));
        const int col = nt * 64 + bn;
        #pragma unroll
        for (int j = 0; j < 16; ++j) {
            const int k = (bk4 << 4) + j;
            bv[j] = (col < Nw) ? f2bf(Wd[(size_t)k * Nw + col]) : (unsigned short)0;
        }
        const int kbB = bk4 << 1;
        *(bf16x8*)&Bs[bn * 64 + (((kbB    ) ^ (bn & 7)) << 3)] = *(bf16x8*)&bv[0];
        *(bf16x8*)&Bs[bn * 64 + (((kbB + 1) ^ (bn & 7)) << 3)] = *(bf16x8*)&bv[8];
    }
    __syncthreads();

    f32x4 acc[2][2];
    #pragma unroll
    for (int i = 0; i < 2; ++i)
        #pragma unroll
        for (int j = 0; j < 2; ++j)
            #pragma unroll
            for (int r = 0; r < 4; ++r) acc[i][j][r] = 0.f;

    #pragma unroll
    for (int ks = 0; ks < 2; ++ks) {
        bf16x8 af[2], bfv[2];
        #pragma unroll
        for (int i = 0; i < 2; ++i) {
            const int row = wm + (i << 4) + lr;
            af[i]  = *(const bf16x8*)&As[row * 64 + ((((ks << 2) + lk) ^ (row & 7)) << 3)];
            const int col = wn + (i << 4) + lr;
            bfv[i] = *(const bf16x8*)&Bs[col * 64 + ((((ks << 2) + lk) ^ (col & 7)) << 3)];
        }
        #pragma unroll
        for (int i = 0; i < 2; ++i)
            #pragma unroll
            for (int j = 0; j < 2; ++j)
                acc[i][j] = __builtin_amdgcn_mfma_f32_16x16x32_bf16(af[i], bfv[j], acc[i][j], 0, 0, 0);
    }

    #pragma unroll
    for (int i = 0; i < 2; ++i)
        #pragma unroll
        for (int j = 0; j < 2; ++j)
            #pragma unroll
            for (int r = 0; r < 4; ++r) {
                const int row = mt * 64 + wm + (i << 4) + (lk << 2) + r;
                const int col = nt * 64 + wn + (j << 4) + lr;
                if (col < Nw) C[(size_t)row * Nw + col] = acc[i][j][r];
            }
}

extern "C" void kernel_launch(void* const* d_in, const int* in_sizes, int n_in,
                              void* d_out, int out_size, void* d_ws, size_t ws_size,
                              hipStream_t stream)
{
    const int Din[3] = {3000, 1000, 500};
    const float* feat[3]   = {(const float*)d_in[0], (const float*)d_in[1], (const float*)d_in[2]};
    const float* adj_sp[3] = {(const float*)d_in[3], (const float*)d_in[5], (const float*)d_in[7]};
    const float* adj_ft[3] = {(const float*)d_in[4], (const float*)d_in[6], (const float*)d_in[8]};
    const int base[3] = {9, 20, 31};
    const float *wconv[3], *bconv[3], *Wenc[3], *g[3], *be[3], *W1[3], *b1[3],
                *W2[3], *b2[3], *alpha[3], *Wdec[3];
    for (int i = 0; i < 3; ++i) {
        wconv[i] = (const float*)d_in[base[i] + 0];
        bconv[i] = (const float*)d_in[base[i] + 1];
        Wenc[i]  = (const float*)d_in[base[i] + 2];
        g[i]     = (const float*)d_in[base[i] + 3];
        be[i]    = (const float*)d_in[base[i] + 4];
        W1[i]    = (const float*)d_in[base[i] + 5];
        b1[i]    = (const float*)d_in[base[i] + 6];
        W2[i]    = (const float*)d_in[base[i] + 7];
        b2[i]    = (const float*)d_in[base[i] + 8];
        alpha[i] = (const float*)d_in[base[i] + 9];
        Wdec[i]  = (const float*)d_in[base[i] + 10];
    }
    const float* Wfc1 = (const float*)d_in[42];
    const float* bfc1 = (const float*)d_in[43];
    const float* Wfc2 = (const float*)d_in[44];
    const float* bfc2 = (const float*)d_in[45];

    // workspace: feb[3] | combb | Tb[3] (bf16), then Cpart (3 * KScap * 1 MB)
    char* wsb = (char*)d_ws;
    const size_t SZ_BF = (size_t)NR * 64 * 2;   // 512 KB
    const size_t SZ_F  = (size_t)NR * 64 * 4;   // 1 MB
    unsigned short* feb   = (unsigned short*)wsb;                    // 3x
    unsigned short* combb = (unsigned short*)(wsb + 3 * SZ_BF);
    unsigned short* Tb    = (unsigned short*)(wsb + 4 * SZ_BF);      // 3x
    float* Cpart          = (float*)(wsb + 7 * SZ_BF);

    int KScap = (int)((ws_size - 7 * SZ_BF) / (3 * SZ_F));
    if (KScap > 8) KScap = 8;                   // KS=8: partial traffic halved
    if (KScap < 1) KScap = 1;

    float* out = (float*)d_out;
    float* emb_out  = out;
    float* comb_out = out + 3 * (size_t)NR * 64;
    O3 rec_out;
    rec_out.p[0] = out + 4 * (size_t)NR * 64;
    rec_out.p[1] = rec_out.p[0] + (size_t)NR * Din[0];
    rec_out.p[2] = rec_out.p[1] + (size_t)NR * Din[1];

    auto split_plan = [&](const int* Ks, I3& kt, I3& tps, I3& nsp, int& maxnsp) {
        maxnsp = 0;
        for (int i = 0; i < 3; ++i) {
            const int k = (Ks[i] + 63) >> 6;
            int t = (k + KScap - 1) / KScap;
            if (k >= 2 && k < 32 && t < 2) t = 2;   // small K: fewer splits
            kt.v[i] = k; tps.v[i] = t;
            nsp.v[i] = (k + t - 1) / t;
            if (nsp.v[i] > maxnsp) maxnsp = nsp.v[i];
        }
    };

    P3 featA, adjspA, adjftA, wcA, bcA, gA, beA, W1A, b1A, W2A, b2A, alA, WdA;
    for (int i = 0; i < 3; ++i) {
        featA.p[i] = feat[i]; adjspA.p[i] = adj_sp[i]; adjftA.p[i] = adj_ft[i];
        wcA.p[i] = wconv[i];  bcA.p[i] = bconv[i];
        gA.p[i] = g[i]; beA.p[i] = be[i]; W1A.p[i] = W1[i]; b1A.p[i] = b1[i];
        W2A.p[i] = W2[i]; b2A.p[i] = b2[i]; alA.p[i] = alpha[i];
        WdA.p[i] = Wdec[i];
    }
    V3 BencV, BfeV, BcombV;
    for (int i = 0; i < 3; ++i) {
        BencV.p[i]  = Wenc[i];
        BfeV.p[i]   = feb + (size_t)i * NR * 64;
        BcombV.p[i] = combb;
    }
    I3 Kfeat = {Din[0], Din[1], Din[2]};
    I3 Kadj  = {NR, NR, NR};
    I3 Dz    = {Din[0], Din[1], Din[2]};

    I3 ktF, tpsF, nspF; int mF; split_plan(Kfeat.v, ktF, tpsF, nspF, mF);
    I3 ktA, tpsA, nspA; int mA; split_plan(Kadj.v,  ktA, tpsA, nspA, mA);

    // 1) fe_i = feat_i @ W_enc_i  (bf16)
    gemm_n64<false, true><<<dim3(64, mF, 3), 256, 0, stream>>>(
        featA, featA, BencV, Cpart, wcA, bcA, Kfeat, ktF, tpsF, KScap);
    reduce_many<<<dim3(256, 3), 256, 0, stream>>>(Cpart, feb, nspF, KScap);

    // 2) gc_i = (w0*adj_sp + w1*adj_ft + b) @ fe_i ; fused CED -> emb_i
    gemm_n64<true, false><<<dim3(64, mA, 3), 256, 0, stream>>>(
        adjspA, adjftA, BfeV, Cpart, wcA, bcA, Kadj, ktA, tpsA, KScap);
    reduce_ced<<<dim3(NR / 4, 3), 256, 0, stream>>>(
        Cpart, gA, beA, W1A, b1A, W2A, b2A, alA, emb_out, nspA, KScap);

    // 3) fusion MLP -> comb (f32 out + bf16 scratch)
    fusion_kernel<<<NR / 4, 256, 0, stream>>>(emb_out, Wfc1, bfc1, Wfc2, bfc2,
                                              comb_out, combb);

    // 4) T_i = adj_sp_i @ comb  (bf16)   [rec = (adj@comb)@Wdec associativity]
    gemm_n64<false, false><<<dim3(64, mA, 3), 256, 0, stream>>>(
        adjspA, adjspA, BcombV, Cpart, wcA, bcA, Kadj, ktA, tpsA, KScap);
    reduce_many<<<dim3(256, 3), 256, 0, stream>>>(Cpart, Tb, nspA, KScap);

    // 5) rec_i = T_i @ W_dec_i
    const int NTmax = (Din[0] + 63) >> 6;
    gemm_rec<<<dim3(64, NTmax, 3), 256, 0, stream>>>(Tb, WdA, rec_out, Dz);
}

// Round 5
// 242.832 us; speedup vs baseline: 1.7665x; 1.0316x over previous
//
#include <hip/hip_runtime.h>

#define NR 4096

typedef __attribute__((ext_vector_type(8))) short bf16x8;
typedef __attribute__((ext_vector_type(4))) float f32x4;
typedef __attribute__((ext_vector_type(4))) unsigned short u16x4;

struct P3 { const float* p[3]; };
struct V3 { const void* p[3]; };
struct O3 { float* p[3]; };
struct I3 { int v[3]; };
struct P6 { const float* p[6]; };
struct U6 { unsigned short* p[6]; };
struct I6 { int v[6]; };

__device__ __forceinline__ unsigned short f2bf(float f) {
    union { float f; unsigned u; } v; v.f = f;
    unsigned r = v.u + 0x7fffu + ((v.u >> 16) & 1u);
    return (unsigned short)(r >> 16);
}

// ---------------------------------------------------------------------------
// C[M,64] = A[M,K] @ B[K,64], z-merged.  A f32 (optional fused dual
// w0*A1+w1*A2+b).  B is PRE-TRANSPOSED bf16 Bt[n=64][k=Kp] -> staging is pure
// vector loads (2x bf16x8) — no scalar B loads (R4's per-iteration tax).
// LDS double-buffered, ONE barrier/iter, prefetch depth 2.
// Split-K partials to Cpart (deterministic).  BM=BN=BK=64, 4 waves 2x2.
// LDS: row-major 64 bf16/row; 16B chunk c of row r at ((c ^ (r&7))<<3).
// CT: write C-partials transposed [64][NR] (used to produce fe^T for the
// next GEMM's Bt without any extra pass; reducer is layout-agnostic).
// ---------------------------------------------------------------------------
template<bool DUAL, bool CT>
__global__ __launch_bounds__(256) void gemm_n64(
    P3 A1a, P3 A2a, V3 Ba, float* __restrict__ Cpart,
    P3 wca, P3 bca, I3 Kz, I3 Kpz, I3 ktz, I3 tpsz, const int KScap)
{
    const int z = blockIdx.z;
    const int K = Kz.v[z], Kp = Kpz.v[z], ktiles = ktz.v[z], tps = tpsz.v[z];
    const int mt = blockIdx.x, sp = blockIdx.y;
    const int kt0 = sp * tps;
    int kt1 = kt0 + tps; if (kt1 > ktiles) kt1 = ktiles;
    if (kt0 >= kt1) return;                     // uniform early-exit
    const int niter = kt1 - kt0;

    __shared__ unsigned short As[2][64 * 64];
    __shared__ unsigned short Bs[2][64 * 64];
    const int t = threadIdx.x;

    const float* __restrict__ A1 = A1a.p[z];
    const float* __restrict__ A2 = DUAL ? A2a.p[z] : A1a.p[z];
    const unsigned short* __restrict__ Bt = (const unsigned short*)Ba.p[z];

    float w0 = 0.f, w1 = 0.f, bb = 0.f;
    if (DUAL) { w0 = wca.p[z][0]; w1 = wca.p[z][1]; bb = bca.p[z][0]; }

    // staging map: rows j*32+sr, k-chunk sc (8 elems) — instruction-contiguous
    const int sr = t >> 3, sc = t & 7;
    // compute maps
    const int l = t & 63, w = t >> 6;
    const int wm = (w >> 1) << 5, wn = (w & 1) << 5;
    const int lr = l & 15, lk = l >> 4;

    const float* Arow1[2] = { A1 + (size_t)(mt * 64 + sr) * K,
                              A1 + (size_t)(mt * 64 + 32 + sr) * K };
    const float* Arow2[2] = { A2 + (size_t)(mt * 64 + sr) * K,
                              A2 + (size_t)(mt * 64 + 32 + sr) * K };
    const unsigned short* Brow[2] = { Bt + (size_t)sr * Kp,
                                      Bt + (size_t)(32 + sr) * Kp };

    f32x4 acc[2][2];
    #pragma unroll
    for (int i = 0; i < 2; ++i)
        #pragma unroll
        for (int j = 0; j < 2; ++j)
            #pragma unroll
            for (int r = 0; r < 4; ++r) acc[i][j][r] = 0.f;

    auto cvt8 = [&](const float* a1, const float* a2, int kk) -> bf16x8 {
        float v[8];
        if (kk + 7 < K) {
            const f32x4 xa = *(const f32x4*)(a1 + kk);
            const f32x4 xb = *(const f32x4*)(a1 + kk + 4);
            if (DUAL) {
                const f32x4 ya = *(const f32x4*)(a2 + kk);
                const f32x4 yb = *(const f32x4*)(a2 + kk + 4);
                #pragma unroll
                for (int e = 0; e < 4; ++e) {
                    v[e]     = w0 * xa[e] + w1 * ya[e] + bb;
                    v[4 + e] = w0 * xb[e] + w1 * yb[e] + bb;
                }
            } else {
                #pragma unroll
                for (int e = 0; e < 4; ++e) { v[e] = xa[e]; v[4 + e] = xb[e]; }
            }
        } else {
            #pragma unroll
            for (int e = 0; e < 8; ++e) {
                const int ki = kk + e;
                const float x1 = (ki < K) ? a1[ki] : 0.f;
                const float x2 = (DUAL && ki < K) ? a2[ki] : 0.f;
                v[e] = DUAL ? (w0 * x1 + w1 * x2 + bb) : x1;
            }
        }
        bf16x8 r;
        #pragma unroll
        for (int e = 0; e < 8; ++e) r[e] = (short)f2bf(v[e]);
        return r;
    };

    auto issue = [&](int kt, bf16x8 (&rA)[2], bf16x8 (&rB)[2]) {
        const int k0 = kt << 6;
        const int kk = k0 + sc * 8;
        #pragma unroll
        for (int j = 0; j < 2; ++j) {
            rB[j] = *(const bf16x8*)(Brow[j] + k0 + sc * 8);
            rA[j] = cvt8(Arow1[j], Arow2[j], kk);
        }
    };

    const int aw0 = sr * 64 + ((sc ^ (sr & 7)) << 3);   // (32+sr)&7 == sr&7
    auto ldsw = [&](int buf, bf16x8 (&rA)[2], bf16x8 (&rB)[2]) {
        *(bf16x8*)&As[buf][aw0]        = rA[0];
        *(bf16x8*)&As[buf][aw0 + 2048] = rA[1];
        *(bf16x8*)&Bs[buf][aw0]        = rB[0];
        *(bf16x8*)&Bs[buf][aw0 + 2048] = rB[1];
    };

    auto domfma = [&](int buf) {
        #pragma unroll
        for (int ks = 0; ks < 2; ++ks) {
            bf16x8 af[2], bfv[2];
            #pragma unroll
            for (int i = 0; i < 2; ++i) {
                const int row = wm + (i << 4) + lr;
                af[i]  = *(const bf16x8*)&As[buf][row * 64 + ((((ks << 2) + lk) ^ (row & 7)) << 3)];
                const int col = wn + (i << 4) + lr;
                bfv[i] = *(const bf16x8*)&Bs[buf][col * 64 + ((((ks << 2) + lk) ^ (col & 7)) << 3)];
            }
            #pragma unroll
            for (int i = 0; i < 2; ++i)
                #pragma unroll
                for (int j = 0; j < 2; ++j)
                    acc[i][j] = __builtin_amdgcn_mfma_f32_16x16x32_bf16(af[i], bfv[j], acc[i][j], 0, 0, 0);
        }
    };

    bf16x8 rA0[2], rB0[2], rA1[2], rB1[2];
    issue(kt0, rA0, rB0);
    ldsw(0, rA0, rB0);
    if (niter > 1) issue(kt0 + 1, rA1, rB1);
    __syncthreads();

    for (int i = 0; i < niter; ++i) {
        if ((i & 1) == 0) {                     // uniform branch (named reg banks)
            if (i + 2 < niter) issue(kt0 + i + 2, rA0, rB0);
            domfma(0);
            if (i + 1 < niter) ldsw(1, rA1, rB1);
        } else {
            if (i + 2 < niter) issue(kt0 + i + 2, rA1, rB1);
            domfma(1);
            if (i + 1 < niter) ldsw(0, rA0, rB0);
        }
        __syncthreads();
    }

    float* Cp = Cpart + (size_t)(z * KScap + sp) * (NR * 64);
    if (CT) {
        #pragma unroll
        for (int i = 0; i < 2; ++i)
            #pragma unroll
            for (int j = 0; j < 2; ++j) {
                const int col = wn + (j << 4) + lr;
                const int row0 = mt * 64 + wm + (i << 4) + (lk << 2);
                *(f32x4*)&Cp[(size_t)col * NR + row0] = acc[i][j];
            }
    } else {
        #pragma unroll
        for (int i = 0; i < 2; ++i)
            #pragma unroll
            for (int j = 0; j < 2; ++j)
                #pragma unroll
                for (int r = 0; r < 4; ++r) {
                    const int row = mt * 64 + wm + (i << 4) + (lk << 2) + r;
                    const int col = wn + (j << 4) + lr;
                    Cp[(size_t)row * 64 + col] = acc[i][j][r];
                }
    }
}

// sum per-z split partials -> bf16 (layout-agnostic), z-merged
__global__ __launch_bounds__(256) void reduce_many(
    const float* __restrict__ Cpart, unsigned short* __restrict__ out,
    I3 nsp, const int KScap)
{
    const int z = blockIdx.y;
    const int idx = (blockIdx.x * 256 + threadIdx.x) * 4;
    const float* base = Cpart + (size_t)z * KScap * (NR * 64);
    const int n = nsp.v[z];
    f32x4 s; s[0] = s[1] = s[2] = s[3] = 0.f;
    for (int sp = 0; sp < n; ++sp)
        s += *(const f32x4*)(base + (size_t)sp * (NR * 64) + idx);
    unsigned short* o = out + (size_t)z * (NR * 64);
    #pragma unroll
    for (int e = 0; e < 4; ++e) o[idx + e] = f2bf(s[e]);
}

// split-reduce fused with CED: gc = sum(partials);
// emb = gc + alpha * (relu(LN(gc)@W1 + b1)@W2 + b2).  One wave per row.
__global__ __launch_bounds__(256) void reduce_ced(
    const float* __restrict__ Cpart, P3 ga, P3 bea, P3 W1a, P3 b1a,
    P3 W2a, P3 b2a, P3 ala, float* __restrict__ emb_out,
    I3 nsp, const int KScap)
{
    __shared__ float ln_s[4][64];
    __shared__ float h_s[4][32];
    const int z = blockIdx.y;
    const int w = threadIdx.x >> 6, l = threadIdx.x & 63;
    const int row = blockIdx.x * 4 + w;
    const float* base = Cpart + (size_t)z * KScap * (NR * 64);
    const int n = nsp.v[z];
    float x = 0.f;
    for (int sp = 0; sp < n; ++sp)
        x += base[(size_t)sp * (NR * 64) + (size_t)row * 64 + l];

    float s = x, s2 = x * x;
    #pragma unroll
    for (int off = 32; off >= 1; off >>= 1) {
        s  += __shfl_xor(s, off);
        s2 += __shfl_xor(s2, off);
    }
    const float mu  = s * (1.f / 64.f);
    const float var = s2 * (1.f / 64.f) - mu * mu;
    const float ln = (x - mu) * rsqrtf(var + 1e-5f) * ga.p[z][l] + bea.p[z][l];
    ln_s[w][l] = ln;
    __syncthreads();
    if (l < 32) {
        const float* W1 = W1a.p[z];
        float h = b1a.p[z][l];
        #pragma unroll 8
        for (int k = 0; k < 64; ++k) h += ln_s[w][k] * W1[k * 32 + l];
        h_s[w][l] = fmaxf(h, 0.f);
    }
    __syncthreads();
    const float* W2 = W2a.p[z];
    float e = b2a.p[z][l];
    #pragma unroll 8
    for (int j = 0; j < 32; ++j) e += h_s[w][j] * W2[j * 64 + l];
    emb_out[(size_t)z * (NR * 64) + (size_t)row * 64 + l] = x + ala.p[z][0] * e;
}

// fusion MLP: comb = (cat @ Wfc1 + b1) @ Wfc2 + b2; emits f32 + combT bf16
__global__ __launch_bounds__(256) void fusion_kernel(
    const float* __restrict__ emb_base, const float* __restrict__ Wfc1,
    const float* __restrict__ bfc1, const float* __restrict__ Wfc2,
    const float* __restrict__ bfc2, float* __restrict__ comb,
    unsigned short* __restrict__ combT)
{
    __shared__ float cat_s[4][192];
    __shared__ float h_s[4][64];
    const int w = threadIdx.x >> 6, l = threadIdx.x & 63;
    const int row = blockIdx.x * 4 + w;
    cat_s[w][l]       = emb_base[(size_t)row * 64 + l];
    cat_s[w][64 + l]  = emb_base[(size_t)(NR * 64) + (size_t)row * 64 + l];
    cat_s[w][128 + l] = emb_base[(size_t)(2 * NR * 64) + (size_t)row * 64 + l];
    __syncthreads();
    float h = bfc1[l];
    #pragma unroll 8
    for (int k = 0; k < 192; ++k) h += cat_s[w][k] * Wfc1[k * 64 + l];
    h_s[w][l] = h;
    __syncthreads();
    float c = bfc2[l];
    #pragma unroll 8
    for (int j = 0; j < 64; ++j) c += h_s[w][j] * Wfc2[j * 64 + l];
    comb[(size_t)row * 64 + l] = c;
    combT[(size_t)l * NR + row] = f2bf(c);      // B^T for step-4 (512 KB, cheap)
}

// generic f32 [R][C] -> bf16 [Cp][Rp] transpose with zero-pad (weights prep)
__global__ __launch_bounds__(256) void prep_t(P6 src, U6 dst, I6 Rv6, I6 Cv6,
                                              I6 Rp6, I6 Cp6)
{
    const int z = blockIdx.y;
    const int Rp = Rp6.v[z], Cp = Cp6.v[z];
    const int rtiles = Rp >> 6, ctiles = Cp >> 6;
    const int tid = blockIdx.x;
    if (tid >= rtiles * ctiles) return;
    const int ci = tid / rtiles, ri = tid % rtiles;
    __shared__ float ld[64][65];
    const int t = threadIdx.x;
    const float* s = src.p[z];
    const int Rv = Rv6.v[z], Cv = Cv6.v[z];
    {
        const int rr = t >> 2;
        const int gr = ri * 64 + rr;
        #pragma unroll
        for (int q = 0; q < 4; ++q) {
            const int cc = (t & 3) * 16 + q * 4;
            const int gc = ci * 64 + cc;
            f32x4 x;
            if (gr < Rv && gc + 3 < Cv) {
                x = *(const f32x4*)(s + (size_t)gr * Cv + gc);
            } else {
                #pragma unroll
                for (int e = 0; e < 4; ++e)
                    x[e] = (gr < Rv && gc + e < Cv) ? s[(size_t)gr * Cv + gc + e] : 0.f;
            }
            #pragma unroll
            for (int e = 0; e < 4; ++e) ld[rr][cc + e] = x[e];
        }
    }
    __syncthreads();
    {
        unsigned short* d = dst.p[z];
        const int cl = t >> 2;
        const int r4 = (t & 3) * 16;
        unsigned short vv[16] __attribute__((aligned(16)));
        #pragma unroll
        for (int e = 0; e < 16; ++e) vv[e] = f2bf(ld[r4 + e][cl]);
        const size_t bpos = (size_t)(ci * 64 + cl) * Rp + ri * 64 + r4;
        *(bf16x8*)&d[bpos]     = *(bf16x8*)&vv[0];
        *(bf16x8*)&d[bpos + 8] = *(bf16x8*)&vv[8];
    }
}

// rec[M,Dz] = Tb[M,64](bf16) @ WdecT_z^T ; B staged from WdecT[Dp][64] bf16.
__global__ __launch_bounds__(256) void gemm_rec(
    const unsigned short* __restrict__ Tbase, V3 WdTa, O3 outa, I3 Dz)
{
    const int z = blockIdx.z;
    const int Nw = Dz.v[z];
    const int mt = blockIdx.x, nt = blockIdx.y;
    if (nt * 64 >= Nw) return;                  // uniform early-exit
    __shared__ unsigned short As[64 * 64];
    __shared__ unsigned short Bs[64 * 64];
    const int t = threadIdx.x;
    const unsigned short* Tb = Tbase + (size_t)z * (NR * 64);
    const unsigned short* Wt = (const unsigned short*)WdTa.p[z];
    float* C = outa.p[z];

    const int sr = t >> 3, sc = t & 7;
    const int l = t & 63, w = t >> 6;
    const int wm = (w >> 1) << 5, wn = (w & 1) << 5;
    const int lr = l & 15, lk = l >> 4;
    const int aw0 = sr * 64 + ((sc ^ (sr & 7)) << 3);

    #pragma unroll
    for (int j = 0; j < 2; ++j) {
        const int m = j * 32 + sr;
        *(bf16x8*)&As[aw0 + j * 2048] = *(const bf16x8*)&Tb[(size_t)(mt * 64 + m) * 64 + sc * 8];
        *(bf16x8*)&Bs[aw0 + j * 2048] = *(const bf16x8*)&Wt[(size_t)(nt * 64 + m) * 64 + sc * 8];
    }
    __syncthreads();

    f32x4 acc[2][2];
    #pragma unroll
    for (int i = 0; i < 2; ++i)
        #pragma unroll
        for (int j = 0; j < 2; ++j)
            #pragma unroll
            for (int r = 0; r < 4; ++r) acc[i][j][r] = 0.f;

    #pragma unroll
    for (int ks = 0; ks < 2; ++ks) {
        bf16x8 af[2], bfv[2];
        #pragma unroll
        for (int i = 0; i < 2; ++i) {
            const int row = wm + (i << 4) + lr;
            af[i]  = *(const bf16x8*)&As[row * 64 + ((((ks << 2) + lk) ^ (row & 7)) << 3)];
            const int col = wn + (i << 4) + lr;
            bfv[i] = *(const bf16x8*)&Bs[col * 64 + ((((ks << 2) + lk) ^ (col & 7)) << 3)];
        }
        #pragma unroll
        for (int i = 0; i < 2; ++i)
            #pragma unroll
            for (int j = 0; j < 2; ++j)
                acc[i][j] = __builtin_amdgcn_mfma_f32_16x16x32_bf16(af[i], bfv[j], acc[i][j], 0, 0, 0);
    }

    #pragma unroll
    for (int i = 0; i < 2; ++i)
        #pragma unroll
        for (int j = 0; j < 2; ++j)
            #pragma unroll
            for (int r = 0; r < 4; ++r) {
                const int row = mt * 64 + wm + (i << 4) + (lk << 2) + r;
                const int col = nt * 64 + wn + (j << 4) + lr;
                if (col < Nw) C[(size_t)row * Nw + col] = acc[i][j][r];
            }
}

extern "C" void kernel_launch(void* const* d_in, const int* in_sizes, int n_in,
                              void* d_out, int out_size, void* d_ws, size_t ws_size,
                              hipStream_t stream)
{
    const int Din[3] = {3000, 1000, 500};
    const int DinP[3] = {3008, 1024, 512};
    const float* feat[3]   = {(const float*)d_in[0], (const float*)d_in[1], (const float*)d_in[2]};
    const float* adj_sp[3] = {(const float*)d_in[3], (const float*)d_in[5], (const float*)d_in[7]};
    const float* adj_ft[3] = {(const float*)d_in[4], (const float*)d_in[6], (const float*)d_in[8]};
    const int base[3] = {9, 20, 31};
    const float *wconv[3], *bconv[3], *Wenc[3], *g[3], *be[3], *W1[3], *b1[3],
                *W2[3], *b2[3], *alpha[3], *Wdec[3];
    for (int i = 0; i < 3; ++i) {
        wconv[i] = (const float*)d_in[base[i] + 0];
        bconv[i] = (const float*)d_in[base[i] + 1];
        Wenc[i]  = (const float*)d_in[base[i] + 2];
        g[i]     = (const float*)d_in[base[i] + 3];
        be[i]    = (const float*)d_in[base[i] + 4];
        W1[i]    = (const float*)d_in[base[i] + 5];
        b1[i]    = (const float*)d_in[base[i] + 6];
        W2[i]    = (const float*)d_in[base[i] + 7];
        b2[i]    = (const float*)d_in[base[i] + 8];
        alpha[i] = (const float*)d_in[base[i] + 9];
        Wdec[i]  = (const float*)d_in[base[i] + 10];
    }
    const float* Wfc1 = (const float*)d_in[42];
    const float* bfc1 = (const float*)d_in[43];
    const float* Wfc2 = (const float*)d_in[44];
    const float* bfc2 = (const float*)d_in[45];

    // workspace: febT[3] | combT | Tb[3] | WencT[3] | WdecT[3] | Cpart
    char* wsb = (char*)d_ws;
    const size_t SZ_BF = (size_t)NR * 64 * 2;   // 512 KB
    const size_t SZ_F  = (size_t)NR * 64 * 4;   // 1 MB
    unsigned short* febT  = (unsigned short*)wsb;                    // 3x
    unsigned short* combT = (unsigned short*)(wsb + 3 * SZ_BF);
    unsigned short* Tb    = (unsigned short*)(wsb + 4 * SZ_BF);      // 3x
    size_t off = 7 * SZ_BF;
    unsigned short* WencT[3]; unsigned short* WdecT[3];
    for (int i = 0; i < 3; ++i) { WencT[i] = (unsigned short*)(wsb + off); off += (size_t)DinP[i] * 64 * 2; }
    for (int i = 0; i < 3; ++i) { WdecT[i] = (unsigned short*)(wsb + off); off += (size_t)DinP[i] * 64 * 2; }
    float* Cpart = (float*)(wsb + ((off + 255) & ~(size_t)255));

    int KScap = (int)((ws_size - ((off + 255) & ~(size_t)255)) / (3 * SZ_F));
    if (KScap > 8) KScap = 8;
    if (KScap < 1) KScap = 1;

    float* out = (float*)d_out;
    float* emb_out  = out;
    float* comb_out = out + 3 * (size_t)NR * 64;
    O3 rec_out;
    rec_out.p[0] = out + 4 * (size_t)NR * 64;
    rec_out.p[1] = rec_out.p[0] + (size_t)NR * Din[0];
    rec_out.p[2] = rec_out.p[1] + (size_t)NR * Din[1];

    auto split_plan = [&](const int* kts, I3& kt, I3& tps, I3& nsp, int& maxnsp) {
        maxnsp = 0;
        for (int i = 0; i < 3; ++i) {
            const int k = kts[i];
            const int t = (k + KScap - 1) / KScap;
            kt.v[i] = k; tps.v[i] = t;
            nsp.v[i] = (k + t - 1) / t;
            if (nsp.v[i] > maxnsp) maxnsp = nsp.v[i];
        }
    };

    P3 featA, adjspA, adjftA, wcA, bcA, gA, beA, W1A, b1A, W2A, b2A, alA;
    for (int i = 0; i < 3; ++i) {
        featA.p[i] = feat[i]; adjspA.p[i] = adj_sp[i]; adjftA.p[i] = adj_ft[i];
        wcA.p[i] = wconv[i];  bcA.p[i] = bconv[i];
        gA.p[i] = g[i]; beA.p[i] = be[i]; W1A.p[i] = W1[i]; b1A.p[i] = b1[i];
        W2A.p[i] = W2[i]; b2A.p[i] = b2[i]; alA.p[i] = alpha[i];
    }
    V3 BencV, BfeV, BcombV, WdTV;
    for (int i = 0; i < 3; ++i) {
        BencV.p[i]  = WencT[i];
        BfeV.p[i]   = febT + (size_t)i * NR * 64;
        BcombV.p[i] = combT;
        WdTV.p[i]   = WdecT[i];
    }
    I3 Kfeat = {Din[0], Din[1], Din[2]};
    I3 KpF   = {DinP[0], DinP[1], DinP[2]};
    I3 Kadj  = {NR, NR, NR};
    I3 Dz    = {Din[0], Din[1], Din[2]};

    const int ktF_[3] = {DinP[0] / 64, DinP[1] / 64, DinP[2] / 64};
    const int ktA_[3] = {64, 64, 64};
    I3 ktF, tpsF, nspF; int mF; split_plan(ktF_, ktF, tpsF, nspF, mF);
    I3 ktA, tpsA, nspA; int mA; split_plan(ktA_, ktA, tpsA, nspA, mA);

    // 0) weight prep: WencT (f32 [Din][64] -> bf16 [64][DinP]),
    //                 WdecT (f32 [64][Din] -> bf16 [DinP][64]), zero-padded
    {
        P6 s6; U6 d6; I6 R6, C6, Rp6, Cp6;
        int maxtiles = 1;
        for (int i = 0; i < 3; ++i) {
            s6.p[i] = Wenc[i]; d6.p[i] = WencT[i];
            R6.v[i] = Din[i]; C6.v[i] = 64; Rp6.v[i] = DinP[i]; Cp6.v[i] = 64;
            s6.p[3 + i] = Wdec[i]; d6.p[3 + i] = WdecT[i];
            R6.v[3 + i] = 64; C6.v[3 + i] = Din[i]; Rp6.v[3 + i] = 64; Cp6.v[3 + i] = DinP[i];
            const int tls = DinP[i] / 64;
            if (tls > maxtiles) maxtiles = tls;
        }
        prep_t<<<dim3(maxtiles, 6), 256, 0, stream>>>(s6, d6, R6, C6, Rp6, Cp6);
    }

    // 1) fe_i = feat_i @ W_enc_i  -> transposed partials -> febT [64][NR]
    gemm_n64<false, true><<<dim3(64, mF, 3), 256, 0, stream>>>(
        featA, featA, BencV, Cpart, wcA, bcA, Kfeat, KpF, ktF, tpsF, KScap);
    reduce_many<<<dim3(256, 3), 256, 0, stream>>>(Cpart, febT, nspF, KScap);

    // 2) gc_i = (w0*adj_sp + w1*adj_ft + b) @ fe_i ; fused CED -> emb_i
    gemm_n64<true, false><<<dim3(64, mA, 3), 256, 0, stream>>>(
        adjspA, adjftA, BfeV, Cpart, wcA, bcA, Kadj, Kadj, ktA, tpsA, KScap);
    reduce_ced<<<dim3(NR / 4, 3), 256, 0, stream>>>(
        Cpart, gA, beA, W1A, b1A, W2A, b2A, alA, emb_out, nspA, KScap);

    // 3) fusion MLP -> comb (f32 out) + combT (bf16 B^T scratch)
    fusion_kernel<<<NR / 4, 256, 0, stream>>>(emb_out, Wfc1, bfc1, Wfc2, bfc2,
                                              comb_out, combT);

    // 4) T_i = adj_sp_i @ comb -> Tb [NR][64] bf16
    gemm_n64<false, false><<<dim3(64, mA, 3), 256, 0, stream>>>(
        adjspA, adjspA, BcombV, Cpart, wcA, bcA, Kadj, Kadj, ktA, tpsA, KScap);
    reduce_many<<<dim3(256, 3), 256, 0, stream>>>(Cpart, Tb, nspA, KScap);

    // 5) rec_i = T_i @ W_dec_i
    const int NTmax = DinP[0] / 64;
    gemm_rec<<<dim3(64, NTmax, 3), 256, 0, stream>>>(Tb, WdTV, rec_out, Dz);
}